// Round 12
// baseline (1091.792 us; speedup 1.0000x reference)
//
#include <hip/hip_runtime.h>
#include <hip/hip_fp16.h>
#include <cstdint>
#include <cstddef>

#define B_    256
#define T_    128
#define SIG_  64
#define MET_  32
#define H_    256
#define F_    16
#define NCOL  1040   // X cols: [i:0..255 | ste:256..511 | c:512..767 | o:768..1023 | fre:1024..1039]

#define NLDS  3      // U slots staged in LDS (48 KB); slots NLDS..31 streamed
#define NSTRM (32 - NLDS)   // 29 streamed slots

__device__ __forceinline__ float hsig(float x) {
    return fminf(fmaxf(x * (1.0f/6.0f) + 0.5f, 0.0f), 1.0f);
}

__device__ __forceinline__ unsigned short f2h(float f) {
    __half h = __float2half(f);
    return *(unsigned short*)&h;
}

__device__ __forceinline__ float ntload_f(const float* p) {
    return __builtin_nontemporal_load(p);
}
__device__ __forceinline__ float4 ntload_f4(const float* p) {
    float4 v;
    v.x = __builtin_nontemporal_load(p + 0);
    v.y = __builtin_nontemporal_load(p + 1);
    v.z = __builtin_nontemporal_load(p + 2);
    v.w = __builtin_nontemporal_load(p + 3);
    return v;
}

// Workgroup barrier WITHOUT the vmcnt(0) drain __syncthreads() forces.
// lgkmcnt(0) makes all LDS ops visible before s_barrier; pending GLOBAL
// loads stay in flight — safe because streamed U is step-invariant.
__device__ __forceinline__ void lbar() {
    asm volatile("s_waitcnt lgkmcnt(0)\n\ts_barrier" ::: "memory");
}

typedef _Float16 half2v __attribute__((ext_vector_type(2)));

__device__ __forceinline__ float dot2(unsigned int u, unsigned int h, float acc) {
#if __has_builtin(__builtin_amdgcn_fdot2)
    return __builtin_amdgcn_fdot2(__builtin_bit_cast(half2v, u),
                                  __builtin_bit_cast(half2v, h), acc, false);
#else
    __half2 uu = *(__half2*)&u, hh = *(__half2*)&h;
    float2 uf = __half22float2(uu), hf = __half22float2(hh);
    return fmaf(uf.x, hf.x, fmaf(uf.y, hf.y, acc));
#endif
}

__device__ __forceinline__ float dot2x4(uint4 u, uint4 h, float acc) {
    acc = dot2(u.x, h.x, acc);
    acc = dot2(u.y, h.y, acc);
    acc = dot2(u.z, h.z, acc);
    acc = dot2(u.w, h.w, acc);
    return acc;
}

// ---------------------------------------------------------------------------
// Pack: Wcat[96][1040] f32, bcat[1040] f32,
// U8: fp16 main cols, [k8][col] uint4 — slot kk at U8[kk*1024+col] holds
//     k=8kk..8kk+7 of col. UF: fp16 fre cols, [col][k] (8 KB, L1-resident).
// ---------------------------------------------------------------------------
__global__ __launch_bounds__(256) void pack_kernel(
    const float* __restrict__ Wis, const float* __restrict__ Wstes, const float* __restrict__ Wfres,
    const float* __restrict__ Wcs, const float* __restrict__ Wos,
    const float* __restrict__ Wim, const float* __restrict__ Wstem, const float* __restrict__ Wfrem,
    const float* __restrict__ Wcm, const float* __restrict__ Wom,
    const float* __restrict__ Ui, const float* __restrict__ Uste, const float* __restrict__ Ufre,
    const float* __restrict__ Uc, const float* __restrict__ Uo,
    const float* __restrict__ bi, const float* __restrict__ bste, const float* __restrict__ bfre,
    const float* __restrict__ bc, const float* __restrict__ bo,
    float* __restrict__ Wcat, float* __restrict__ bcat,
    unsigned short* __restrict__ U8, unsigned short* __restrict__ UF)
{
    int gtid = blockIdx.x * blockDim.x + threadIdx.x;
    int stride = gridDim.x * blockDim.x;
    const float* Wsig[5] = {Wis, Wstes, Wcs, Wos, Wfres};
    const float* Wmet[5] = {Wim, Wstem, Wcm, Wom, Wfrem};
    const float* Us[4]   = {Ui, Uste, Uc, Uo};
    const float* bs[5]   = {bi, bste, bc, bo, bfre};

    for (int i = gtid; i < 96*NCOL; i += stride) {
        int k = i / NCOL, n = i - k*NCOL;
        int sec, idx, secN;
        if (n < 1024) { sec = n >> 8; idx = n & 255; secN = H_; }
        else          { sec = 4; idx = n - 1024; secN = F_; }
        float v = (k < 64) ? Wsig[sec][k*secN + idx] : Wmet[sec][(k-64)*secN + idx];
        Wcat[k*NCOL + n] = v;
    }
    for (int n = gtid; n < NCOL; n += stride) {
        int sec, idx;
        if (n < 1024) { sec = n >> 8; idx = n & 255; }
        else          { sec = 4; idx = n - 1024; }
        bcat[n] = bs[sec][idx];
    }
    for (int i = gtid; i < 1024*H_; i += stride) {
        int col = i >> 8, k = i & 255;
        int sec = col >> 8, idx = col & 255;
        U8[(((k >> 3) * 1024) + col) * 8 + (k & 7)] = f2h(Us[sec][k*H_ + idx]);
    }
    for (int i = gtid; i < 16*H_; i += stride) {
        int col = i >> 8, k = i & 255;
        UF[col*H_ + k] = f2h(Ufre[k*F_ + col]);
    }
}

// ---------------------------------------------------------------------------
// Phase 1: input projection GEMM for ALL time steps.
// ---------------------------------------------------------------------------
__global__ __launch_bounds__(256) void proj_kernel(
    const float* __restrict__ sig, const float* __restrict__ met,
    const float* __restrict__ Wcat, const float* __restrict__ bcat,
    float* __restrict__ X)
{
    __shared__ float A_s[32][128];
    __shared__ float W_s[32][128];
    int tid = threadIdx.x;
    int c0b = blockIdx.x * 128;
    int m0  = blockIdx.y * 128;
    int t0  = blockIdx.z * 16;
    int r0  = (tid >> 4) * 8;
    int c0t = (tid & 15) * 8;

    float acc[8][8];
    #pragma unroll
    for (int i = 0; i < 8; ++i)
        #pragma unroll
        for (int j = 0; j < 8; ++j) acc[i][j] = 0.0f;

    for (int k0 = 0; k0 < 96; k0 += 32) {
        for (int idx = tid; idx < 32*128; idx += 256) {
            int ml = idx & 127, kk = idx >> 7;
            int m = m0 + ml;
            int b = m >> 4, tl = m & 15;
            int g = b * T_ + t0 + tl;
            int k = k0 + kk;
            float v = (k < 64) ? sig[g*SIG_ + k] : met[g*MET_ + (k - 64)];
            A_s[kk][ml] = v;
        }
        for (int idx = tid; idx < 32*128; idx += 256) {
            int c = idx & 127, kk = idx >> 7;
            int n = c0b + c;
            W_s[kk][c] = (n < NCOL) ? Wcat[(k0+kk)*NCOL + n] : 0.0f;
        }
        __syncthreads();
        #pragma unroll
        for (int kk = 0; kk < 32; ++kk) {
            float4 a0 = *(const float4*)&A_s[kk][r0];
            float4 a1 = *(const float4*)&A_s[kk][r0+4];
            float4 w0 = *(const float4*)&W_s[kk][c0t];
            float4 w1 = *(const float4*)&W_s[kk][c0t+4];
            float av[8] = {a0.x,a0.y,a0.z,a0.w,a1.x,a1.y,a1.z,a1.w};
            float wv[8] = {w0.x,w0.y,w0.z,w0.w,w1.x,w1.y,w1.z,w1.w};
            #pragma unroll
            for (int i = 0; i < 8; ++i)
                #pragma unroll
                for (int j = 0; j < 8; ++j)
                    acc[i][j] = fmaf(av[i], wv[j], acc[i][j]);
        }
        __syncthreads();
    }
    #pragma unroll
    for (int i = 0; i < 8; ++i) {
        int m = m0 + r0 + i;
        int bb = m >> 4, tl = m & 15;
        size_t row = (size_t)bb * T_ + t0 + tl;
        #pragma unroll
        for (int j = 0; j < 8; ++j) {
            int n = c0b + c0t + j;
            if (n < NCOL) X[row*NCOL + n] = acc[i][j] + bcat[n];
        }
    }
}

// ---------------------------------------------------------------------------
// Phase 2: full recurrence, SINGLE launch, grid=256 x 1024 threads.
// R12 change vs R11: per-block ROTATED k-sweep. R11 showed a BW wall at
// ~19 TB/s L2 aggregate (55% of ceiling): all 256 blocks sweep the same U
// addresses in the same order in barrier-locked phase -> same-line requests
// from 32 CUs/XCD serialize on one L2 channel while others idle. Rotating
// each block's start slot ((blockIdx>>3)%29: same-XCD blocks spread over
// all 29 slots) spreads the instantaneous working point across channels.
// fp summation order changes (harmless at 18x error margin).
// ---------------------------------------------------------------------------
__global__ __launch_bounds__(1024) void recur_kernel(
    const float* __restrict__ X, const uint4* __restrict__ U8,
    const uint4* __restrict__ UF,
    const float* __restrict__ U_a, const float* __restrict__ b_a,
    const float* __restrict__ W_p, const float* __restrict__ b_p,
    const float* __restrict__ fc_w, const float* __restrict__ fc_b,
    float* __restrict__ out)
{
    __shared__ uint4 ldsU[NLDS * 1024];  // 49,152 B
    __shared__ float pre_s[1024];        //  4,096 B
    __shared__ uint4 h_p4[H_/8];         //    512 B (h as fp16 pairs)
    __shared__ float qp[64];             //    256 B (fre quarter partials)
    __shared__ float cs_s[16], sn_s[16]; //    128 B   (total 54,144 B)

    int tid  = threadIdx.x;
    int b    = blockIdx.x;
    int lane = tid & 63;
    int wid  = tid >> 6;
    bool isfre = ((lane & 15) == 15);
    int fq = lane >> 4;                  // quarter 0..3 (when isfre)

    int j  = tid >> 2;                   // update row
    int f0 = (tid & 3) * 4;              // update f range

    // de-phase: same-XCD blocks (b%8 equal) get spread start slots
    int kstart = NLDS + ((b >> 3) % NSTRM);   // in [NLDS, 32)

    // stage LDS U tier (slots 0..NLDS-1)
    #pragma unroll
    for (int d = 0; d < NLDS; ++d)
        ldsU[d * 1024 + tid] = U8[d * 1024 + tid];

    if (tid < H_/8) { uint4 z; z.x=z.y=z.z=z.w=0u; h_p4[tid] = z; }
    if (tid < 16) {
        float ang = (float)tid * 0.39269908169872414f; // 2*pi/16
        cs_s[tid] = cosf(ang);
        sn_s[tid] = sinf(ang);
    }
    float Sre[4], Sim[4];
    #pragma unroll
    for (int r = 0; r < 4; ++r) { Sre[r] = 0.0f; Sim[r] = 0.0f; }

    float ba_j = b_a[j];
    float4 ua4 = ((const float4*)U_a)[tid & 3];
    const uint4* Uf = UF + (wid * 32 + fq * 8);
    const float* Xb = X + (size_t)b * T_ * NCOL;
    __half* h_h = (__half*)h_p4;

    float hnew = 0.0f;
    __syncthreads();

    for (int t = 0; t < T_; ++t) {
        const float* xrow = Xb + (size_t)t * NCOL;

        // ---- dot phase: pre[col=tid] = x + U[:,col] . h ----
        float acc = ntload_f(&xrow[tid]);
        // streamed tier, rotated: [kstart..32) then [NLDS..kstart)
        #pragma unroll 4
        for (int kk = kstart; kk < 32; ++kk) {
            uint4 u = U8[kk * 1024 + tid];
            acc = dot2x4(u, h_p4[kk], acc);
        }
        #pragma unroll 4
        for (int kk = NLDS; kk < kstart; ++kk) {
            uint4 u = U8[kk * 1024 + tid];
            acc = dot2x4(u, h_p4[kk], acc);
        }
        // LDS tier
        #pragma unroll
        for (int d = 0; d < NLDS; ++d) {
            uint4 u = ldsU[d * 1024 + tid];
            acc = dot2x4(u, h_p4[d], acc);
        }
        float fa = 0.0f;
        if (isfre) {
            #pragma unroll
            for (int q = 0; q < 8; ++q)
                fa = dot2x4(Uf[q], h_p4[fq * 8 + q], fa);
        }
        pre_s[tid] = acc;
        if (isfre) qp[wid*4 + fq] = fa;
        lbar();   // A: pre_s + qp visible; h_p4 reads done (lgkm only)

        // ---- update phase ----
        float xi   = pre_s[j];
        float xste = pre_s[256 + j];
        float xc   = pre_s[512 + j];
        float xo   = pre_s[768 + j];
        float gi   = hsig(xi);
        float gste = hsig(xste);
        float go   = hsig(xo);
        float cc   = gi * tanhf(xc);

        float4 xfre = ntload_f4(&xrow[1024 + f0]);
        float4 q0 = *(const float4*)&qp[(f0+0)*4];
        float4 q1 = *(const float4*)&qp[(f0+1)*4];
        float4 q2 = *(const float4*)&qp[(f0+2)*4];
        float4 q3 = *(const float4*)&qp[(f0+3)*4];
        float fre[4];
        fre[0] = hsig(xfre.x + q0.x + q0.y + q0.z + q0.w);
        fre[1] = hsig(xfre.y + q1.x + q1.y + q1.z + q1.w);
        fre[2] = hsig(xfre.z + q2.x + q2.y + q2.z + q2.w);
        fre[3] = hsig(xfre.w + q3.x + q3.y + q3.z + q3.w);

        int tt1 = (t + 1) & 15;
        float Aa = 0.0f;
        #pragma unroll
        for (int r = 0; r < 4; ++r) {
            int idx = (tt1 * (f0 + r)) & 15;
            float dec = gste * fre[r];
            float sre = fmaf(dec, Sre[r], cc * cs_s[idx]);
            float sim = fmaf(dec, Sim[r], cc * sn_s[idx]);
            Sre[r] = sre; Sim[r] = sim;
            Aa = fmaf(fmaf(sre, sre, sim*sim), ((const float*)&ua4)[r], Aa);
        }
        Aa += __shfl_xor(Aa, 1);
        Aa += __shfl_xor(Aa, 2);
        if ((tid & 3) == 0) {
            float a = tanhf(Aa + ba_j);
            hnew = go * a;
            h_h[j] = __float2half(hnew);
        }
        lbar();   // B: h visible for next step (lgkm only)
    }

    // ---- head: out[b] = (sum_j h[j]*W_p[j] + b_p)*fc_w + fc_b ----
    if ((tid & 3) == 0) pre_s[j] = hnew * W_p[j];
    __syncthreads();
    for (int s = 128; s > 0; s >>= 1) {
        if (tid < s) pre_s[tid] += pre_s[tid + s];
        __syncthreads();
    }
    if (tid == 0) out[b] = (pre_s[0] + b_p[0]) * fc_w[0] + fc_b[0];
}

// ---------------------------------------------------------------------------
extern "C" void kernel_launch(void* const* d_in, const int* in_sizes, int n_in,
                              void* d_out, int out_size, void* d_ws, size_t ws_size,
                              hipStream_t stream) {
    const float* signal = (const float*)d_in[0];
    const float* metmast = (const float*)d_in[1];
    const float* W_i_s   = (const float*)d_in[2];
    const float* W_ste_s = (const float*)d_in[3];
    const float* W_fre_s = (const float*)d_in[4];
    const float* W_c_s   = (const float*)d_in[5];
    const float* W_o_s   = (const float*)d_in[6];
    const float* W_i_m   = (const float*)d_in[7];
    const float* W_ste_m = (const float*)d_in[8];
    const float* W_fre_m = (const float*)d_in[9];
    const float* W_c_m   = (const float*)d_in[10];
    const float* W_o_m   = (const float*)d_in[11];
    const float* U_i   = (const float*)d_in[12];
    const float* b_i   = (const float*)d_in[13];
    const float* U_ste = (const float*)d_in[14];
    const float* b_ste = (const float*)d_in[15];
    const float* U_fre = (const float*)d_in[16];
    const float* b_fre = (const float*)d_in[17];
    const float* U_c   = (const float*)d_in[18];
    const float* b_c   = (const float*)d_in[19];
    const float* U_o   = (const float*)d_in[20];
    const float* b_o   = (const float*)d_in[21];
    const float* U_a   = (const float*)d_in[22];
    const float* b_a   = (const float*)d_in[23];
    const float* W_p   = (const float*)d_in[24];
    const float* b_p   = (const float*)d_in[25];
    const float* fc_w  = (const float*)d_in[26];
    const float* fc_b  = (const float*)d_in[27];
    float* out = (float*)d_out;

    char* ws = (char*)d_ws;
    float*          Wcat = (float*)(ws + 0);                 //  96*1040*4 = 399360
    float*          bcat = (float*)(ws + 399360);            //  4160 -> 403520
    unsigned short* U8   = (unsigned short*)(ws + 403520);   //  1024*256*2 = 524288 -> 927808
    unsigned short* UF   = (unsigned short*)(ws + 927808);   //  16*256*2 = 8192 -> 936000
    float*          X    = (float*)(ws + 936000);            //  256*128*1040*4 = 136314880
    // total ~137.3 MB

    pack_kernel<<<256, 256, 0, stream>>>(
        W_i_s, W_ste_s, W_fre_s, W_c_s, W_o_s,
        W_i_m, W_ste_m, W_fre_m, W_c_m, W_o_m,
        U_i, U_ste, U_fre, U_c, U_o,
        b_i, b_ste, b_fre, b_c, b_o,
        Wcat, bcat, U8, UF);

    proj_kernel<<<dim3(9, 32, 8), 256, 0, stream>>>(signal, metmast, Wcat, bcat, X);

    recur_kernel<<<B_, 1024, 0, stream>>>(X, (const uint4*)U8, (const uint4*)UF,
                                          U_a, b_a, W_p, b_p, fc_w, fc_b, out);
}

// Round 14
// 1082.961 us; speedup vs baseline: 1.0082x; 1.0082x over previous
//
#include <hip/hip_runtime.h>
#include <hip/hip_fp16.h>
#include <cstdint>
#include <cstddef>

#define B_    256
#define T_    128
#define SIG_  64
#define MET_  32
#define H_    256
#define F_    16
#define NCOL  1040   // X cols: [i:0..255 | ste:256..511 | c:512..767 | o:768..1023 | fre:1024..1039]

#define NLDS  3      // fp16 U slots staged in LDS (48 KB); slots 3..31 are fp8-streamed
#define NSTRM (32 - NLDS)

// fp8 path: e4m3, values pre-scaled by 64, decoded with HW cvt (exact
// through f16). Streamed tier bytes/step: 472 KB -> 232 KB.
#if __has_builtin(__builtin_amdgcn_cvt_pk_f32_fp8) && __has_builtin(__builtin_amdgcn_cvt_pk_fp8_f32) && __has_builtin(__builtin_amdgcn_cvt_pkrtz)
#define HAVE_FP8 1
#else
#define HAVE_FP8 0
#endif

typedef float  f2v  __attribute__((ext_vector_type(2)));
typedef _Float16 half2v __attribute__((ext_vector_type(2)));

__device__ __forceinline__ float hsig(float x) {
    return fminf(fmaxf(x * (1.0f/6.0f) + 0.5f, 0.0f), 1.0f);
}

__device__ __forceinline__ unsigned short f2h(float f) {
    __half h = __float2half(f);
    return *(unsigned short*)&h;
}

__device__ __forceinline__ float ntload_f(const float* p) {
    return __builtin_nontemporal_load(p);
}
__device__ __forceinline__ float4 ntload_f4(const float* p) {
    float4 v;
    v.x = __builtin_nontemporal_load(p + 0);
    v.y = __builtin_nontemporal_load(p + 1);
    v.z = __builtin_nontemporal_load(p + 2);
    v.w = __builtin_nontemporal_load(p + 3);
    return v;
}

// Workgroup barrier WITHOUT the vmcnt(0) drain __syncthreads() forces.
__device__ __forceinline__ void lbar() {
    asm volatile("s_waitcnt lgkmcnt(0)\n\ts_barrier" ::: "memory");
}

__device__ __forceinline__ float dot2(unsigned int u, unsigned int h, float acc) {
#if __has_builtin(__builtin_amdgcn_fdot2)
    return __builtin_amdgcn_fdot2(__builtin_bit_cast(half2v, u),
                                  __builtin_bit_cast(half2v, h), acc, false);
#else
    __half2 uu = *(__half2*)&u, hh = *(__half2*)&h;
    float2 uf = __half22float2(uu), hf = __half22float2(hh);
    return fmaf(uf.x, hf.x, fmaf(uf.y, hf.y, acc));
#endif
}

__device__ __forceinline__ float dot2x4(uint4 u, uint4 h, float acc) {
    acc = dot2(u.x, h.x, acc);
    acc = dot2(u.y, h.y, acc);
    acc = dot2(u.z, h.z, acc);
    acc = dot2(u.w, h.w, acc);
    return acc;
}

// decode two e4m3 bytes (compile-time-selected half of w) -> packed f16 pair
template <bool HI>
__device__ __forceinline__ unsigned int fp8pair2h2(unsigned int w) {
#if HAVE_FP8
    f2v f = __builtin_amdgcn_cvt_pk_f32_fp8((int)w, HI);
    auto h = __builtin_amdgcn_cvt_pkrtz(f.x, f.y);   // exact: e4m3 subset of f16
    return __builtin_bit_cast(unsigned int, h);
#else
    unsigned int bsel = HI ? (w >> 16) : (w & 0xffffu);
    unsigned int sp = ((bsel & 0xffu) << 8) | ((bsel & 0xff00u) << 16);
    return (sp & 0x80008000u) | (((sp & 0x7f007f00u) >> 1) + 0x20002000u);
#endif
}

// encode float -> e4m3 byte (pack-time only)
__device__ __forceinline__ unsigned int f2e4m3(float x) {
#if HAVE_FP8
    return (unsigned int)(__builtin_amdgcn_cvt_pk_fp8_f32(x, x, 0, false) & 0xff);
#else
    unsigned int bb = __float_as_uint(x);
    unsigned int s = (bb >> 24) & 0x80u;
    unsigned int m = bb & 0x7fffffffu;
    if (m < 0x3c800000u) return s | 0x08u;     // clamp small to +-2^-6 (fallback decode has no subnormals)
    unsigned int r = m + 0x7ffffu + ((m >> 20) & 1u);
    int ee = (int)(r >> 23) - 120;
    if (ee > 15) return s | 0x7eu;
    return s | ((unsigned int)ee << 3) | ((r >> 20) & 7u);
#endif
}

// ---------------------------------------------------------------------------
// Pack: Wcat[96][1040] f32, bcat[1040] f32,
// U8 (fp16): slots 0..2  — [k8][col] uint4, k=0..23 (LDS tier).
// UQ (fp8) : slots 3..31 — [(kk-3)][col] uint2 = 8 e4m3 bytes of 64*U.
// UF (fp16): fre cols [col][k] (8 KB, L1-resident).
// ---------------------------------------------------------------------------
__global__ __launch_bounds__(256) void pack_kernel(
    const float* __restrict__ Wis, const float* __restrict__ Wstes, const float* __restrict__ Wfres,
    const float* __restrict__ Wcs, const float* __restrict__ Wos,
    const float* __restrict__ Wim, const float* __restrict__ Wstem, const float* __restrict__ Wfrem,
    const float* __restrict__ Wcm, const float* __restrict__ Wom,
    const float* __restrict__ Ui, const float* __restrict__ Uste, const float* __restrict__ Ufre,
    const float* __restrict__ Uc, const float* __restrict__ Uo,
    const float* __restrict__ bi, const float* __restrict__ bste, const float* __restrict__ bfre,
    const float* __restrict__ bc, const float* __restrict__ bo,
    float* __restrict__ Wcat, float* __restrict__ bcat,
    unsigned short* __restrict__ U8, unsigned short* __restrict__ UQ,
    unsigned short* __restrict__ UF)
{
    int gtid = blockIdx.x * blockDim.x + threadIdx.x;
    int stride = gridDim.x * blockDim.x;
    const float* Wsig[5] = {Wis, Wstes, Wcs, Wos, Wfres};
    const float* Wmet[5] = {Wim, Wstem, Wcm, Wom, Wfrem};
    const float* Us[4]   = {Ui, Uste, Uc, Uo};
    const float* bs[5]   = {bi, bste, bc, bo, bfre};

    for (int i = gtid; i < 96*NCOL; i += stride) {
        int k = i / NCOL, n = i - k*NCOL;
        int sec, idx, secN;
        if (n < 1024) { sec = n >> 8; idx = n & 255; secN = H_; }
        else          { sec = 4; idx = n - 1024; secN = F_; }
        float v = (k < 64) ? Wsig[sec][k*secN + idx] : Wmet[sec][(k-64)*secN + idx];
        Wcat[k*NCOL + n] = v;
    }
    for (int n = gtid; n < NCOL; n += stride) {
        int sec, idx;
        if (n < 1024) { sec = n >> 8; idx = n & 255; }
        else          { sec = 4; idx = n - 1024; }
        bcat[n] = bs[sec][idx];
    }
    // fp16 LDS-tier slots: k = 0..23
    for (int i = gtid; i < 1024*24; i += stride) {
        int col = i & 1023, k = i >> 10;
        int sec = col >> 8, idx = col & 255;
        U8[(((k >> 3) * 1024) + col) * 8 + (k & 7)] = f2h(Us[sec][k*H_ + idx]);
    }
    // fp8 streamed slots: k = 24..255 as pairs (116 pairs per col)
    for (int i = gtid; i < 1024*116; i += stride) {
        int col = i & 1023, pi = i >> 10;
        int k0 = 24 + 2*pi;
        int kk = k0 >> 3, p = (k0 & 7) >> 1;
        int sec = col >> 8, idx = col & 255;
        float v0 = Us[sec][k0*H_ + idx] * 64.0f;
        float v1 = Us[sec][(k0+1)*H_ + idx] * 64.0f;
        UQ[(((kk - NLDS) * 1024) + col) * 4 + p] =
            (unsigned short)(f2e4m3(v0) | (f2e4m3(v1) << 8));
    }
    // fre 16 cols (fp16)
    for (int i = gtid; i < 16*H_; i += stride) {
        int col = i >> 8, k = i & 255;
        UF[col*H_ + k] = f2h(Ufre[k*F_ + col]);
    }
}

// ---------------------------------------------------------------------------
// Phase 1: input projection GEMM for ALL time steps.
// ---------------------------------------------------------------------------
__global__ __launch_bounds__(256) void proj_kernel(
    const float* __restrict__ sig, const float* __restrict__ met,
    const float* __restrict__ Wcat, const float* __restrict__ bcat,
    float* __restrict__ X)
{
    __shared__ float A_s[32][128];
    __shared__ float W_s[32][128];
    int tid = threadIdx.x;
    int c0b = blockIdx.x * 128;
    int m0  = blockIdx.y * 128;
    int t0  = blockIdx.z * 16;
    int r0  = (tid >> 4) * 8;
    int c0t = (tid & 15) * 8;

    float acc[8][8];
    #pragma unroll
    for (int i = 0; i < 8; ++i)
        #pragma unroll
        for (int j = 0; j < 8; ++j) acc[i][j] = 0.0f;

    for (int k0 = 0; k0 < 96; k0 += 32) {
        for (int idx = tid; idx < 32*128; idx += 256) {
            int ml = idx & 127, kk = idx >> 7;
            int m = m0 + ml;
            int b = m >> 4, tl = m & 15;
            int g = b * T_ + t0 + tl;
            int k = k0 + kk;
            float v = (k < 64) ? sig[g*SIG_ + k] : met[g*MET_ + (k - 64)];
            A_s[kk][ml] = v;
        }
        for (int idx = tid; idx < 32*128; idx += 256) {
            int c = idx & 127, kk = idx >> 7;
            int n = c0b + c;
            W_s[kk][c] = (n < NCOL) ? Wcat[(k0+kk)*NCOL + n] : 0.0f;
        }
        __syncthreads();
        #pragma unroll
        for (int kk = 0; kk < 32; ++kk) {
            float4 a0 = *(const float4*)&A_s[kk][r0];
            float4 a1 = *(const float4*)&A_s[kk][r0+4];
            float4 w0 = *(const float4*)&W_s[kk][c0t];
            float4 w1 = *(const float4*)&W_s[kk][c0t+4];
            float av[8] = {a0.x,a0.y,a0.z,a0.w,a1.x,a1.y,a1.z,a1.w};
            float wv[8] = {w0.x,w0.y,w0.z,w0.w,w1.x,w1.y,w1.z,w1.w};
            #pragma unroll
            for (int i = 0; i < 8; ++i)
                #pragma unroll
                for (int j = 0; j < 8; ++j)
                    acc[i][j] = fmaf(av[i], wv[j], acc[i][j]);
        }
        __syncthreads();
    }
    #pragma unroll
    for (int i = 0; i < 8; ++i) {
        int m = m0 + r0 + i;
        int bb = m >> 4, tl = m & 15;
        size_t row = (size_t)bb * T_ + t0 + tl;
        #pragma unroll
        for (int j = 0; j < 8; ++j) {
            int n = c0b + c0t + j;
            if (n < NCOL) X[row*NCOL + n] = acc[i][j] + bcat[n];
        }
    }
}

// ---------------------------------------------------------------------------
// Phase 2: full recurrence, SINGLE launch, grid=256 x 1024 threads.
// R14 = R13 with compile fixes (templated constant word_sel; bit_cast pkrtz
// result). Streamed U tier is fp8 e4m3 (x64 pre-scale) -> 232 KB/CU/step
// (was 472). R11/R12 proved the wall is the per-CU ingest path (~31 B/cyc);
// fewer bytes is the only lever. LDS tier (k 0..23) stays exact fp16.
// Accumulate fp8 tier separately, scale by 1/64 once. No register tier
// (VGPR cap 64 at 1024 thr — R8-R10).
// ---------------------------------------------------------------------------
__global__ __launch_bounds__(1024) void recur_kernel(
    const float* __restrict__ X, const uint4* __restrict__ U8,
    const uint2* __restrict__ UQ, const uint4* __restrict__ UF,
    const float* __restrict__ U_a, const float* __restrict__ b_a,
    const float* __restrict__ W_p, const float* __restrict__ b_p,
    const float* __restrict__ fc_w, const float* __restrict__ fc_b,
    float* __restrict__ out)
{
    __shared__ uint4 ldsU[NLDS * 1024];  // 49,152 B
    __shared__ float pre_s[1024];        //  4,096 B
    __shared__ uint4 h_p4[H_/8];         //    512 B (h as fp16 pairs)
    __shared__ float qp[64];             //    256 B (fre quarter partials)
    __shared__ float cs_s[16], sn_s[16]; //    128 B   (total 54,144 B)

    int tid  = threadIdx.x;
    int b    = blockIdx.x;
    int lane = tid & 63;
    int wid  = tid >> 6;
    bool isfre = ((lane & 15) == 15);
    int fq = lane >> 4;                  // quarter 0..3 (when isfre)

    int j  = tid >> 2;                   // update row
    int f0 = (tid & 3) * 4;              // update f range

    // stage LDS U tier (fp16 slots 0..NLDS-1)
    #pragma unroll
    for (int d = 0; d < NLDS; ++d)
        ldsU[d * 1024 + tid] = U8[d * 1024 + tid];

    if (tid < H_/8) { uint4 z; z.x=z.y=z.z=z.w=0u; h_p4[tid] = z; }
    if (tid < 16) {
        float ang = (float)tid * 0.39269908169872414f; // 2*pi/16
        cs_s[tid] = cosf(ang);
        sn_s[tid] = sinf(ang);
    }
    float Sre[4], Sim[4];
    #pragma unroll
    for (int r = 0; r < 4; ++r) { Sre[r] = 0.0f; Sim[r] = 0.0f; }

    float ba_j = b_a[j];
    float4 ua4 = ((const float4*)U_a)[tid & 3];
    const uint4* Uf = UF + (wid * 32 + fq * 8);
    const float* Xb = X + (size_t)b * T_ * NCOL;
    __half* h_h = (__half*)h_p4;

    float hnew = 0.0f;
    __syncthreads();

    for (int t = 0; t < T_; ++t) {
        const float* xrow = Xb + (size_t)t * NCOL;

        // ---- dot phase: pre[col=tid] = x + U[:,col] . h ----
        float acc  = ntload_f(&xrow[tid]);
        float accq = 0.0f;
        // fp8 streamed tier (slots NLDS..31): loads pipeline across lbar()
        #pragma unroll 8
        for (int kk = NLDS; kk < 32; ++kk) {
            uint2 u = UQ[(kk - NLDS) * 1024 + tid];
            uint4 hp = h_p4[kk];
            accq = dot2(fp8pair2h2<false>(u.x), hp.x, accq);
            accq = dot2(fp8pair2h2<true >(u.x), hp.y, accq);
            accq = dot2(fp8pair2h2<false>(u.y), hp.z, accq);
            accq = dot2(fp8pair2h2<true >(u.y), hp.w, accq);
        }
        // fp16 LDS tier (slots 0..NLDS-1)
        #pragma unroll
        for (int d = 0; d < NLDS; ++d) {
            uint4 u = ldsU[d * 1024 + tid];
            acc = dot2x4(u, h_p4[d], acc);
        }
        acc = fmaf(accq, 0.015625f, acc);   // undo x64 pre-scale

        float fa = 0.0f;
        if (isfre) {
            #pragma unroll
            for (int q = 0; q < 8; ++q)
                fa = dot2x4(Uf[q], h_p4[fq * 8 + q], fa);
        }
        pre_s[tid] = acc;
        if (isfre) qp[wid*4 + fq] = fa;
        lbar();   // A: pre_s + qp visible; h_p4 reads done (lgkm only)

        // ---- update phase ----
        float xi   = pre_s[j];
        float xste = pre_s[256 + j];
        float xc   = pre_s[512 + j];
        float xo   = pre_s[768 + j];
        float gi   = hsig(xi);
        float gste = hsig(xste);
        float go   = hsig(xo);
        float cc   = gi * tanhf(xc);

        float4 xfre = ntload_f4(&xrow[1024 + f0]);
        float4 q0 = *(const float4*)&qp[(f0+0)*4];
        float4 q1 = *(const float4*)&qp[(f0+1)*4];
        float4 q2 = *(const float4*)&qp[(f0+2)*4];
        float4 q3 = *(const float4*)&qp[(f0+3)*4];
        float fre[4];
        fre[0] = hsig(xfre.x + q0.x + q0.y + q0.z + q0.w);
        fre[1] = hsig(xfre.y + q1.x + q1.y + q1.z + q1.w);
        fre[2] = hsig(xfre.z + q2.x + q2.y + q2.z + q2.w);
        fre[3] = hsig(xfre.w + q3.x + q3.y + q3.z + q3.w);

        int tt1 = (t + 1) & 15;
        float Aa = 0.0f;
        #pragma unroll
        for (int r = 0; r < 4; ++r) {
            int idx = (tt1 * (f0 + r)) & 15;
            float dec = gste * fre[r];
            float sre = fmaf(dec, Sre[r], cc * cs_s[idx]);
            float sim = fmaf(dec, Sim[r], cc * sn_s[idx]);
            Sre[r] = sre; Sim[r] = sim;
            Aa = fmaf(fmaf(sre, sre, sim*sim), ((const float*)&ua4)[r], Aa);
        }
        Aa += __shfl_xor(Aa, 1);
        Aa += __shfl_xor(Aa, 2);
        if ((tid & 3) == 0) {
            float a = tanhf(Aa + ba_j);
            hnew = go * a;
            h_h[j] = __float2half(hnew);
        }
        lbar();   // B: h visible for next step (lgkm only)
    }

    // ---- head: out[b] = (sum_j h[j]*W_p[j] + b_p)*fc_w + fc_b ----
    if ((tid & 3) == 0) pre_s[j] = hnew * W_p[j];
    __syncthreads();
    for (int s = 128; s > 0; s >>= 1) {
        if (tid < s) pre_s[tid] += pre_s[tid + s];
        __syncthreads();
    }
    if (tid == 0) out[b] = (pre_s[0] + b_p[0]) * fc_w[0] + fc_b[0];
}

// ---------------------------------------------------------------------------
extern "C" void kernel_launch(void* const* d_in, const int* in_sizes, int n_in,
                              void* d_out, int out_size, void* d_ws, size_t ws_size,
                              hipStream_t stream) {
    const float* signal = (const float*)d_in[0];
    const float* metmast = (const float*)d_in[1];
    const float* W_i_s   = (const float*)d_in[2];
    const float* W_ste_s = (const float*)d_in[3];
    const float* W_fre_s = (const float*)d_in[4];
    const float* W_c_s   = (const float*)d_in[5];
    const float* W_o_s   = (const float*)d_in[6];
    const float* W_i_m   = (const float*)d_in[7];
    const float* W_ste_m = (const float*)d_in[8];
    const float* W_fre_m = (const float*)d_in[9];
    const float* W_c_m   = (const float*)d_in[10];
    const float* W_o_m   = (const float*)d_in[11];
    const float* U_i   = (const float*)d_in[12];
    const float* b_i   = (const float*)d_in[13];
    const float* U_ste = (const float*)d_in[14];
    const float* b_ste = (const float*)d_in[15];
    const float* U_fre = (const float*)d_in[16];
    const float* b_fre = (const float*)d_in[17];
    const float* U_c   = (const float*)d_in[18];
    const float* b_c   = (const float*)d_in[19];
    const float* U_o   = (const float*)d_in[20];
    const float* b_o   = (const float*)d_in[21];
    const float* U_a   = (const float*)d_in[22];
    const float* b_a   = (const float*)d_in[23];
    const float* W_p   = (const float*)d_in[24];
    const float* b_p   = (const float*)d_in[25];
    const float* fc_w  = (const float*)d_in[26];
    const float* fc_b  = (const float*)d_in[27];
    float* out = (float*)d_out;

    char* ws = (char*)d_ws;
    float*          Wcat = (float*)(ws + 0);                 //  399360
    float*          bcat = (float*)(ws + 399360);            //  4160   -> 403520
    unsigned short* U8   = (unsigned short*)(ws + 403520);   //  49152  -> 452672
    unsigned short* UQ   = (unsigned short*)(ws + 452672);   //  237568 -> 690240
    unsigned short* UF   = (unsigned short*)(ws + 690240);   //  8192   -> 698432
    float*          X    = (float*)(ws + 698432);            //  136314880 -> ~137.0 MB

    pack_kernel<<<256, 256, 0, stream>>>(
        W_i_s, W_ste_s, W_fre_s, W_c_s, W_o_s,
        W_i_m, W_ste_m, W_fre_m, W_c_m, W_o_m,
        U_i, U_ste, U_fre, U_c, U_o,
        b_i, b_ste, b_fre, b_c, b_o,
        Wcat, bcat, U8, UQ, UF);

    proj_kernel<<<dim3(9, 32, 8), 256, 0, stream>>>(signal, metmast, Wcat, bcat, X);

    recur_kernel<<<B_, 1024, 0, stream>>>(X, (const uint4*)U8, (const uint2*)UQ,
                                          (const uint4*)UF,
                                          U_a, b_a, W_p, b_p, fc_w, fc_b, out);
}